// Round 4
// baseline (320.335 us; speedup 1.0000x reference)
//
#include <hip/hip_runtime.h>

#define FD 20
#define DD 64

#define GA 64     // gram partials for A (users)  = GAB blocks * 4 waves
#define GB 128    // gram partials for B (items)  = GBB blocks * 4 waves
#define GAB 16    // gram blocks for A
#define GBB 32    // gram blocks for B
#define POSB 2048 // pos blocks in fused mid kernel
#define NEGB 64   // reducer blocks (one Gram row each) -- fused into mid
#define TOTALB (GAB + GBB + POSB)

typedef float float2v __attribute__((ext_vector_type(2)));
typedef float float4v __attribute__((ext_vector_type(4)));
typedef unsigned short ushort4v __attribute__((ext_vector_type(4)));
typedef unsigned short ushort8v __attribute__((ext_vector_type(8)));
typedef short short8v __attribute__((ext_vector_type(8)));

__device__ __forceinline__ unsigned short f2bf(float f) {
    unsigned u = __float_as_uint(f);
    unsigned r = u + 0x7fffu + ((u >> 16) & 1u);   // round-to-nearest-even
    return (unsigned short)(r >> 16);
}
__device__ __forceinline__ float bf2f(unsigned short h) {
    return __uint_as_float((unsigned)h << 16);
}

// ---------------------------------------------------------------------------
// Kernel 0: fp32 -> fp8 e4m3 (OCP) conversion of both embedding tables via
// HW v_cvt_pk_fp8_f32, plus zero-init of d_out and the done-counter.
// ---------------------------------------------------------------------------
__global__ __launch_bounds__(256) void conv_kernel(
    const float* __restrict__ ue, const float* __restrict__ ie,
    unsigned int* __restrict__ u8, unsigned int* __restrict__ i8,
    int n4, float* __restrict__ out, int out_size,
    unsigned int* __restrict__ done)
{
    int i = blockIdx.x * blockDim.x + threadIdx.x;
    if (i < out_size) out[i] = 0.0f;
    if (i == 0) *done = 0u;
    if (i >= 2 * n4) return;
    const float4v* src; unsigned int* dst; int k;
    if (i < n4) { src = (const float4v*)ue; dst = u8; k = i; }
    else        { src = (const float4v*)ie; dst = i8; k = i - n4; }
    float4v v = src[k];
    unsigned int p = 0;
    p = __builtin_amdgcn_cvt_pk_fp8_f32(v.x, v.y, p, false);  // bytes 0,1
    p = __builtin_amdgcn_cvt_pk_fp8_f32(v.z, v.w, p, true);   // bytes 2,3
    dst[k] = p;
}

// ---------------------------------------------------------------------------
// Kernel 1 (unchanged from r3): 4 entities per wave, 16 lanes each.
// ---------------------------------------------------------------------------
__global__ __launch_bounds__(256, 4) void entity_kernel(
    const unsigned char* __restrict__ user_f8,
    const unsigned char* __restrict__ item_f8,
    const float* __restrict__ w_user, const float* __restrict__ w_item,
    const float* __restrict__ bias, const float* __restrict__ h1,
    const int* __restrict__ ufeat, const int* __restrict__ ifeat,
    unsigned short* __restrict__ p_bf, float* __restrict__ su,
    unsigned short* __restrict__ q_bf, float* __restrict__ sv,
    int U, int V)
{
    int gwid = (int)((blockIdx.x * blockDim.x + threadIdx.x) >> 6);
    int lane = threadIdx.x & 63;
    int eg   = lane >> 4;            // entity slot within wave: 0..3
    int c    = lane & 15;            // dim chunk (4 dims)
    int ent  = gwid * 4 + eg;
    if (ent >= U + V) return;

    bool isU = ent < U;
    int  m   = isU ? ent : ent - U;
    const unsigned char* emb = isU ? user_f8 : item_f8;
    const float* wv   = isU ? w_user : w_item;
    const int*   fidx = (isU ? ufeat : ifeat) + (size_t)m * FD;
    float extra       = isU ? bias[0] : 0.0f;
    unsigned short* srow = (isU ? p_bf : q_bf) + (size_t)m * DD;
    float* sc         = (isU ? su : sv) + m;

    int idx[FD];
#pragma unroll
    for (int j = 0; j < FD; ++j) idx[j] = fidx[j];

    unsigned int hw[FD];
#pragma unroll
    for (int j = 0; j < FD; ++j)
        hw[j] = *((const unsigned int*)(emb + (size_t)idx[j] * DD) + c);

    float4v s4 = (float4v)0.0f, ss4 = (float4v)0.0f;
#pragma unroll
    for (int j = 0; j < FD; ++j) {
        float2v lo = __builtin_amdgcn_cvt_pk_f32_fp8(hw[j], false);
        float2v hi = __builtin_amdgcn_cvt_pk_f32_fp8(hw[j], true);
        float4v g;
        g.x = lo.x; g.y = lo.y; g.z = hi.x; g.w = hi.y;
        s4 += g; ss4 += g * g;
    }

    float part = wv[idx[c]];
    if (c < FD - 16) part += wv[idx[16 + c]];

    float4v h14 = *(const float4v*)(h1 + c * 4);
    float4v bi4 = 0.5f * (s4 * s4 - ss4);
    part += bi4.x*h14.x + bi4.y*h14.y + bi4.z*h14.z + bi4.w*h14.w;

#pragma unroll
    for (int off = 1; off <= 8; off <<= 1)
        part += __shfl_xor(part, off, 64);

    ushort4v o;
    o.x = f2bf(s4.x); o.y = f2bf(s4.y); o.z = f2bf(s4.z); o.w = f2bf(s4.w);
    *(ushort4v*)(srow + c * 4) = o;

    if (c == 0) *sc = part + extra;
}

// ---------------------------------------------------------------------------
// MFMA Gram partial, LDS-FREE (unchanged from r2/r3).
// ---------------------------------------------------------------------------
__device__ __forceinline__ void gram_block_mfma(
    const unsigned short* __restrict__ M, int nrows, int gwid, int nw,
    float* __restrict__ Gpart)
{
    int lane = threadIdx.x & 63;
    int q = lane >> 4;
    int c = lane & 15;

    float4v acc[4][4];
#pragma unroll
    for (int ti = 0; ti < 4; ++ti)
#pragma unroll
        for (int tj = 0; tj < 4; ++tj)
            acc[ti][tj] = (float4v)0.0f;

    int ntiles = (nrows + 63) >> 6;
    for (int tt = gwid; tt < ntiles; tt += nw) {
        int row0 = tt << 6;
#pragma unroll
        for (int kb = 0; kb < 2; ++kb) {
            int r0 = row0 + kb * 32 + q * 8;
            const unsigned short* base = M + (size_t)r0 * DD + c;
            short8v f[4];
            if (row0 + 64 <= nrows) {
#pragma unroll
                for (int Db = 0; Db < 4; ++Db)
#pragma unroll
                    for (int j = 0; j < 8; ++j)
                        f[Db][j] = (short)base[(size_t)j * DD + Db * 16];
            } else {
#pragma unroll
                for (int Db = 0; Db < 4; ++Db)
#pragma unroll
                    for (int j = 0; j < 8; ++j)
                        f[Db][j] = (r0 + j < nrows)
                                 ? (short)base[(size_t)j * DD + Db * 16]
                                 : (short)0;
            }
#pragma unroll
            for (int ti = 0; ti < 4; ++ti)
#pragma unroll
                for (int tj = 0; tj < 4; ++tj)
                    acc[ti][tj] = __builtin_amdgcn_mfma_f32_16x16x32_bf16(
                        f[ti], f[tj], acc[ti][tj], 0, 0, 0);
        }
    }

    float* out = Gpart + (size_t)gwid * (DD * DD);
#pragma unroll
    for (int ti = 0; ti < 4; ++ti)
#pragma unroll
        for (int tj = 0; tj < 4; ++tj)
#pragma unroll
            for (int rg = 0; rg < 4; ++rg)
                out[(ti * 16 + q * 4 + rg) * DD + tj * 16 + c] = acc[ti][tj][rg];
}

// ---------------------------------------------------------------------------
// Kernel 2 (fused): gram blocks + pos blocks + fused final reduce.
// Completion protocol: release-fence, atomicAdd(done); the LAST 64
// incrementers each take one Gram row, spin until done==TOTALB
// (relaxed load + s_sleep), acquire-fence, then run the reduce logic
// (identical arithmetic/order to the old neg_reduce_kernel).
// ---------------------------------------------------------------------------
__global__ __launch_bounds__(256) void mid_kernel(
    const unsigned short* __restrict__ p_bf, int U, float* __restrict__ PA,
    const unsigned short* __restrict__ q_bf, int V, float* __restrict__ PB,
    const float* __restrict__ su, const float* __restrict__ sv,
    const float* __restrict__ h2,
    const int* __restrict__ pu, const int* __restrict__ pi,
    int P, float* __restrict__ posPart,
    unsigned int* __restrict__ done, float* __restrict__ out)
{
    __shared__ float red[4];
    __shared__ float sA[4][64], sB[4][64];
    __shared__ float sPos;
    __shared__ unsigned int s_old;
    int w = threadIdx.x >> 6;
    int lane = threadIdx.x & 63;

    if (blockIdx.x < GAB) {
        gram_block_mfma(p_bf, U, blockIdx.x * 4 + w, GA, PA);
    } else if (blockIdx.x < GAB + GBB) {
        gram_block_mfma(q_bf, V, (blockIdx.x - GAB) * 4 + w, GB, PB);
    } else {
        // ---- positive-pair part ----
        int sl   = lane & 15;
        int sub  = lane >> 4;
        int pb   = blockIdx.x - (GAB + GBB);
        int wId  = pb * 4 + w;
        const int NW = POSB * 4;                 // 8192 waves

        float4v h2v = *(const float4v*)(h2 + sl * 4);

        int pid0 = wId * 4 + sub;                // [0, 32768)
        int pid1 = pid0 + NW * 4;                // [32768, 65536)
        bool ok0 = pid0 < P, ok1 = pid1 < P;

        int u0 = 0, v0 = 0, u1 = 0, v1 = 0;
        if (ok0) { u0 = pu[pid0]; v0 = pi[pid0]; }
        if (ok1) { u1 = pu[pid1]; v1 = pi[pid1]; }

        ushort4v ph0 = (ushort4v)0, qh0 = (ushort4v)0;
        ushort4v ph1 = (ushort4v)0, qh1 = (ushort4v)0;
        if (ok0) {
            ph0 = *(const ushort4v*)(p_bf + (size_t)u0 * DD + sl * 4);
            qh0 = *(const ushort4v*)(q_bf + (size_t)v0 * DD + sl * 4);
        }
        if (ok1) {
            ph1 = *(const ushort4v*)(p_bf + (size_t)u1 * DD + sl * 4);
            qh1 = *(const ushort4v*)(q_bf + (size_t)v1 * DD + sl * 4);
        }

        float d0 = bf2f(ph0.x)*bf2f(qh0.x)*h2v.x + bf2f(ph0.y)*bf2f(qh0.y)*h2v.y
                 + bf2f(ph0.z)*bf2f(qh0.z)*h2v.z + bf2f(ph0.w)*bf2f(qh0.w)*h2v.w;
        float d1 = bf2f(ph1.x)*bf2f(qh1.x)*h2v.x + bf2f(ph1.y)*bf2f(qh1.y)*h2v.y
                 + bf2f(ph1.z)*bf2f(qh1.z)*h2v.z + bf2f(ph1.w)*bf2f(qh1.w)*h2v.w;
#pragma unroll
        for (int off = 1; off < 16; off <<= 1) {
            d0 += __shfl_xor(d0, off, 64);
            d1 += __shfl_xor(d1, off, 64);
        }

        float acc = 0.0f;
        if (sl == 0) {
            if (ok0) { float y = d0 + su[u0] + sv[v0]; acc += 0.5f * y * y - 2.0f * y; }
            if (ok1) { float y = d1 + su[u1] + sv[v1]; acc += 0.5f * y * y - 2.0f * y; }
        }
        acc += __shfl_xor(acc, 16, 64);
        acc += __shfl_xor(acc, 32, 64);
        if (lane == 0) red[w] = acc;
        __syncthreads();
        if (threadIdx.x == 0)
            posPart[pb] = red[0] + red[1] + red[2] + red[3];
    }

    // ---- completion protocol ----
    __threadfence();                       // release: make partials visible
    __syncthreads();
    if (threadIdx.x == 0)
        s_old = atomicAdd(done, 1u);
    __syncthreads();
    unsigned int old = s_old;
    if (old < (unsigned)(TOTALB - NEGB)) return;
    int rid = (int)(old - (unsigned)(TOTALB - NEGB));   // 0..63: Gram row

    if (threadIdx.x == 0) {
        while (__hip_atomic_load(done, __ATOMIC_RELAXED,
                                 __HIP_MEMORY_SCOPE_AGENT) < (unsigned)TOTALB)
            __builtin_amdgcn_s_sleep(2);
    }
    __syncthreads();
    __threadfence();                       // acquire: see all partials

    // ---- final reduce for Gram row rid (identical to old neg_reduce) ----
    int t  = threadIdx.x;
    int l  = t & 63;
    int ch = t >> 6;                       // k-chunk 0..3
    int e  = rid * 64 + l;                 // Gram entry, i=rid, j=l

    float a = 0.0f, b = 0.0f;
#pragma unroll
    for (int k = 0; k < GA / 4; ++k)       // 16 coalesced loads
        a += PA[(size_t)(ch * (GA / 4) + k) * (DD * DD) + e];
#pragma unroll
    for (int k = 0; k < GB / 4; ++k)       // 32 coalesced loads
        b += PB[(size_t)(ch * (GB / 4) + k) * (DD * DD) + e];
    sA[ch][l] = a;
    sB[ch][l] = b;

    if (ch == 1) {                         // wave 1: fold 32 pos partials
        float p = (l < POSB / NEGB) ? posPart[rid * (POSB / NEGB) + l] : 0.0f;
#pragma unroll
        for (int off = 1; off <= 32; off <<= 1)
            p += __shfl_xor(p, off, 64);
        if (l == 0) sPos = p;
    }
    __syncthreads();

    if (ch == 0) {
        float fa = sA[0][l] + sA[1][l] + sA[2][l] + sA[3][l];
        float fb = sB[0][l] + sB[1][l] + sB[2][l] + sB[3][l];
        float acc = 0.5f * h2[rid] * h2[l] * fa * fb;
#pragma unroll
        for (int off = 1; off <= 32; off <<= 1)
            acc += __shfl_xor(acc, off, 64);
        if (l == 0)
            atomicAdd(out, acc + sPos);
    }
}

extern "C" void kernel_launch(void* const* d_in, const int* in_sizes, int n_in,
                              void* d_out, int out_size, void* d_ws, size_t ws_size,
                              hipStream_t stream)
{
    const float* user_emb = (const float*)d_in[0];
    const float* item_emb = (const float*)d_in[1];
    const float* w_user   = (const float*)d_in[2];
    const float* w_item   = (const float*)d_in[3];
    const float* bias     = (const float*)d_in[4];
    const float* h1       = (const float*)d_in[5];
    const float* h2       = (const float*)d_in[6];
    const int*   ufeat    = (const int*)d_in[7];
    const int*   ifeat    = (const int*)d_in[8];
    const int*   pu       = (const int*)d_in[9];
    const int*   pi       = (const int*)d_in[10];

    const int NF = in_sizes[0] / DD;
    const int U  = in_sizes[7] / FD;
    const int V  = in_sizes[8] / FD;
    const int P  = in_sizes[9];

    float* ws = (float*)d_ws;
    size_t off = 0;
    unsigned short* p_bf = (unsigned short*)(ws + off); off += (size_t)U * DD / 2;
    unsigned short* q_bf = (unsigned short*)(ws + off); off += (size_t)V * DD / 2;
    float* su   = ws + off; off += (size_t)U;          off = (off + 63) & ~(size_t)63;
    float* sv   = ws + off; off += (size_t)V;          off = (off + 63) & ~(size_t)63;
    float* PA   = ws + off; off += (size_t)GA * DD * DD;
    float* PB   = ws + off; off += (size_t)GB * DD * DD;
    float* posPart = ws + off; off += (size_t)POSB;    off = (off + 63) & ~(size_t)63;
    unsigned int* done = (unsigned int*)(ws + off);    off += 16;
    unsigned char* uf8 = (unsigned char*)(ws + off);   off += (size_t)NF * DD / 4;
    unsigned char* if8 = (unsigned char*)(ws + off);   off += (size_t)NF * DD / 4;

    float* out = (float*)d_out;

    int n4 = NF * DD / 4;
    conv_kernel<<<(2 * n4 + 255) / 256, 256, 0, stream>>>(
        user_emb, item_emb, (unsigned int*)uf8, (unsigned int*)if8,
        n4, out, out_size, done);

    int nent = U + V;
    int nwaves = (nent + 3) / 4;             // 4 entities per wave
    entity_kernel<<<(nwaves + 3) / 4, 256, 0, stream>>>(
        uf8, if8, w_user, w_item, bias, h1,
        ufeat, ifeat, p_bf, su, q_bf, sv, U, V);

    mid_kernel<<<TOTALB, 256, 0, stream>>>(
        p_bf, U, PA, q_bf, V, PB, su, sv, h2, pu, pi, P, posPart,
        done, out);
}

// Round 5
// 156.496 us; speedup vs baseline: 2.0469x; 2.0469x over previous
//
#include <hip/hip_runtime.h>

#define FD 20
#define DD 64

#define GA 64     // gram partials for A (users)  = GAB blocks * 4 waves
#define GB 128    // gram partials for B (items)  = GBB blocks * 4 waves
#define GAB 16    // gram blocks for A
#define GBB 32    // gram blocks for B
#define POSB 2048 // pos blocks in fused mid kernel
#define NEGB 64   // neg reduce blocks (one Gram row each)

typedef float float2v __attribute__((ext_vector_type(2)));
typedef float float4v __attribute__((ext_vector_type(4)));
typedef unsigned short ushort4v __attribute__((ext_vector_type(4)));
typedef unsigned short ushort8v __attribute__((ext_vector_type(8)));
typedef short short8v __attribute__((ext_vector_type(8)));

__device__ __forceinline__ unsigned short f2bf(float f) {
    unsigned u = __float_as_uint(f);
    unsigned r = u + 0x7fffu + ((u >> 16) & 1u);   // round-to-nearest-even
    return (unsigned short)(r >> 16);
}
__device__ __forceinline__ float bf2f(unsigned short h) {
    return __uint_as_float((unsigned)h << 16);
}

// ---------------------------------------------------------------------------
// Kernel 1: per-entity FM terms, DIRECT fp32 gathers (no conversion pass).
// 4 entities per wave, 16 lanes each; lane (e,c) owns dims [4c,4c+4) across
// all 20 features -> s/ss lane-local, 20 independent 16B gathers in flight.
// Block 0 additionally zero-inits d_out (stream-ordered before neg_reduce).
// ---------------------------------------------------------------------------
__global__ __launch_bounds__(256) void entity_kernel(
    const float* __restrict__ user_emb,
    const float* __restrict__ item_emb,
    const float* __restrict__ w_user, const float* __restrict__ w_item,
    const float* __restrict__ bias, const float* __restrict__ h1,
    const int* __restrict__ ufeat, const int* __restrict__ ifeat,
    unsigned short* __restrict__ p_bf, float* __restrict__ su,
    unsigned short* __restrict__ q_bf, float* __restrict__ sv,
    int U, int V, float* __restrict__ out, int out_size)
{
    if (blockIdx.x == 0)
        for (int i = threadIdx.x; i < out_size; i += 256) out[i] = 0.0f;

    int gwid = (int)((blockIdx.x * blockDim.x + threadIdx.x) >> 6);
    int lane = threadIdx.x & 63;
    int eg   = lane >> 4;            // entity slot within wave: 0..3
    int c    = lane & 15;            // dim chunk (4 dims)
    int ent  = gwid * 4 + eg;
    if (ent >= U + V) return;

    bool isU = ent < U;
    int  m   = isU ? ent : ent - U;
    const float* emb  = isU ? user_emb : item_emb;
    const float* wv   = isU ? w_user : w_item;
    const int*   fidx = (isU ? ufeat : ifeat) + (size_t)m * FD;
    float extra       = isU ? bias[0] : 0.0f;
    unsigned short* srow = (isU ? p_bf : q_bf) + (size_t)m * DD;
    float* sc         = (isU ? su : sv) + m;

    int idx[FD];
#pragma unroll
    for (int j = 0; j < FD; ++j) idx[j] = fidx[j];

    // 20 independent 16B gathers, all in flight
    float4v g[FD];
#pragma unroll
    for (int j = 0; j < FD; ++j)
        g[j] = *(const float4v*)(emb + (size_t)idx[j] * DD + c * 4);

    float4v s4 = (float4v)0.0f, ss4 = (float4v)0.0f;
#pragma unroll
    for (int j = 0; j < FD; ++j) {
        s4 += g[j]; ss4 += g[j] * g[j];
    }

    // first-order w sum: lane c covers j=c, lanes 0..3 also j=16+c
    float part = wv[idx[c]];
    if (c < FD - 16) part += wv[idx[16 + c]];

    // bi-interaction dot h1 (lane-local 4 dims)
    float4v h14 = *(const float4v*)(h1 + c * 4);
    float4v bi4 = 0.5f * (s4 * s4 - ss4);
    part += bi4.x*h14.x + bi4.y*h14.y + bi4.z*h14.z + bi4.w*h14.w;

    // 16-lane group reduce (stays within the entity's lane group)
#pragma unroll
    for (int off = 1; off <= 8; off <<= 1)
        part += __shfl_xor(part, off, 64);

    // bf16 row store: 64 lanes -> 4 rows x 128B
    ushort4v o;
    o.x = f2bf(s4.x); o.y = f2bf(s4.y); o.z = f2bf(s4.z); o.w = f2bf(s4.w);
    *(ushort4v*)(srow + c * 4) = o;

    if (c == 0) *sc = part + extra;
}

// ---------------------------------------------------------------------------
// MFMA Gram partial, LDS-FREE (unchanged from r2/r3): one wave per 64-row
// tile stride; A-frag == B-frag; full 4x4 MFMA grid; full 64x64 partial.
// C/D layout (m89-verified, r1-r3-passed): col = lane&15, row = (lane>>4)*4+reg.
// ---------------------------------------------------------------------------
__device__ __forceinline__ void gram_block_mfma(
    const unsigned short* __restrict__ M, int nrows, int gwid, int nw,
    float* __restrict__ Gpart)
{
    int lane = threadIdx.x & 63;
    int q = lane >> 4;
    int c = lane & 15;

    float4v acc[4][4];
#pragma unroll
    for (int ti = 0; ti < 4; ++ti)
#pragma unroll
        for (int tj = 0; tj < 4; ++tj)
            acc[ti][tj] = (float4v)0.0f;

    int ntiles = (nrows + 63) >> 6;
    for (int tt = gwid; tt < ntiles; tt += nw) {
        int row0 = tt << 6;
#pragma unroll
        for (int kb = 0; kb < 2; ++kb) {
            int r0 = row0 + kb * 32 + q * 8;
            const unsigned short* base = M + (size_t)r0 * DD + c;
            short8v f[4];
            if (row0 + 64 <= nrows) {
#pragma unroll
                for (int Db = 0; Db < 4; ++Db)
#pragma unroll
                    for (int j = 0; j < 8; ++j)
                        f[Db][j] = (short)base[(size_t)j * DD + Db * 16];
            } else {
#pragma unroll
                for (int Db = 0; Db < 4; ++Db)
#pragma unroll
                    for (int j = 0; j < 8; ++j)
                        f[Db][j] = (r0 + j < nrows)
                                 ? (short)base[(size_t)j * DD + Db * 16]
                                 : (short)0;
            }
#pragma unroll
            for (int ti = 0; ti < 4; ++ti)
#pragma unroll
                for (int tj = 0; tj < 4; ++tj)
                    acc[ti][tj] = __builtin_amdgcn_mfma_f32_16x16x32_bf16(
                        f[ti], f[tj], acc[ti][tj], 0, 0, 0);
        }
    }

    float* out = Gpart + (size_t)gwid * (DD * DD);
#pragma unroll
    for (int ti = 0; ti < 4; ++ti)
#pragma unroll
        for (int tj = 0; tj < 4; ++tj)
#pragma unroll
            for (int rg = 0; rg < 4; ++rg)
                out[(ti * 16 + q * 4 + rg) * DD + tj * 16 + c] = acc[ti][tj][rg];
}

// ---------------------------------------------------------------------------
// Kernel 2 (fused, identical to r3): gram blocks + pos blocks.
// ---------------------------------------------------------------------------
__global__ __launch_bounds__(256) void mid_kernel(
    const unsigned short* __restrict__ p_bf, int U, float* __restrict__ PA,
    const unsigned short* __restrict__ q_bf, int V, float* __restrict__ PB,
    const float* __restrict__ su, const float* __restrict__ sv,
    const float* __restrict__ h2,
    const int* __restrict__ pu, const int* __restrict__ pi,
    int P, float* __restrict__ posPart)
{
    __shared__ float red[4];
    int w = threadIdx.x >> 6;

    if (blockIdx.x < GAB) {
        gram_block_mfma(p_bf, U, blockIdx.x * 4 + w, GA, PA);
        return;
    }
    if (blockIdx.x < GAB + GBB) {
        gram_block_mfma(q_bf, V, (blockIdx.x - GAB) * 4 + w, GB, PB);
        return;
    }

    // ---- positive-pair part ----
    int lane = threadIdx.x & 63;
    int sl   = lane & 15;
    int sub  = lane >> 4;
    int pb   = blockIdx.x - (GAB + GBB);
    int wId  = pb * 4 + w;
    const int NW = POSB * 4;                 // 8192 waves

    float4v h2v = *(const float4v*)(h2 + sl * 4);

    int pid0 = wId * 4 + sub;                // [0, 32768)
    int pid1 = pid0 + NW * 4;                // [32768, 65536)
    bool ok0 = pid0 < P, ok1 = pid1 < P;

    int u0 = 0, v0 = 0, u1 = 0, v1 = 0;
    if (ok0) { u0 = pu[pid0]; v0 = pi[pid0]; }
    if (ok1) { u1 = pu[pid1]; v1 = pi[pid1]; }

    ushort4v ph0 = (ushort4v)0, qh0 = (ushort4v)0;
    ushort4v ph1 = (ushort4v)0, qh1 = (ushort4v)0;
    if (ok0) {
        ph0 = *(const ushort4v*)(p_bf + (size_t)u0 * DD + sl * 4);
        qh0 = *(const ushort4v*)(q_bf + (size_t)v0 * DD + sl * 4);
    }
    if (ok1) {
        ph1 = *(const ushort4v*)(p_bf + (size_t)u1 * DD + sl * 4);
        qh1 = *(const ushort4v*)(q_bf + (size_t)v1 * DD + sl * 4);
    }

    float d0 = bf2f(ph0.x)*bf2f(qh0.x)*h2v.x + bf2f(ph0.y)*bf2f(qh0.y)*h2v.y
             + bf2f(ph0.z)*bf2f(qh0.z)*h2v.z + bf2f(ph0.w)*bf2f(qh0.w)*h2v.w;
    float d1 = bf2f(ph1.x)*bf2f(qh1.x)*h2v.x + bf2f(ph1.y)*bf2f(qh1.y)*h2v.y
             + bf2f(ph1.z)*bf2f(qh1.z)*h2v.z + bf2f(ph1.w)*bf2f(qh1.w)*h2v.w;
#pragma unroll
    for (int off = 1; off < 16; off <<= 1) {
        d0 += __shfl_xor(d0, off, 64);
        d1 += __shfl_xor(d1, off, 64);
    }

    float acc = 0.0f;
    if (sl == 0) {
        if (ok0) { float y = d0 + su[u0] + sv[v0]; acc += 0.5f * y * y - 2.0f * y; }
        if (ok1) { float y = d1 + su[u1] + sv[v1]; acc += 0.5f * y * y - 2.0f * y; }
    }
    acc += __shfl_xor(acc, 16, 64);
    acc += __shfl_xor(acc, 32, 64);
    if (lane == 0) red[w] = acc;
    __syncthreads();
    if (threadIdx.x == 0)
        posPart[pb] = red[0] + red[1] + red[2] + red[3];
}

// ---------------------------------------------------------------------------
// Kernel 3 (identical to r3): reduce gram partials + pos partials.
// ---------------------------------------------------------------------------
__global__ __launch_bounds__(256) void neg_reduce_kernel(
    const float* __restrict__ PA, const float* __restrict__ PB,
    const float* __restrict__ h2, const float* __restrict__ posPart,
    float* __restrict__ out)
{
    __shared__ float sA[4][64], sB[4][64];
    __shared__ float sPos;
    int t  = threadIdx.x;
    int l  = t & 63;
    int ch = t >> 6;                       // k-chunk 0..3
    int e  = blockIdx.x * 64 + l;          // Gram entry, i=blockIdx.x, j=l

    float a = 0.0f, b = 0.0f;
#pragma unroll
    for (int k = 0; k < GA / 4; ++k)       // 16 coalesced loads
        a += PA[(size_t)(ch * (GA / 4) + k) * (DD * DD) + e];
#pragma unroll
    for (int k = 0; k < GB / 4; ++k)       // 32 coalesced loads
        b += PB[(size_t)(ch * (GB / 4) + k) * (DD * DD) + e];
    sA[ch][l] = a;
    sB[ch][l] = b;

    if (ch == 1) {                         // wave 1: fold 32 pos partials
        float p = (l < POSB / NEGB) ? posPart[blockIdx.x * (POSB / NEGB) + l] : 0.0f;
#pragma unroll
        for (int off = 1; off <= 32; off <<= 1)
            p += __shfl_xor(p, off, 64);
        if (l == 0) sPos = p;
    }
    __syncthreads();

    if (ch == 0) {
        float fa = sA[0][l] + sA[1][l] + sA[2][l] + sA[3][l];
        float fb = sB[0][l] + sB[1][l] + sB[2][l] + sB[3][l];
        float acc = 0.5f * h2[blockIdx.x] * h2[l] * fa * fb;
#pragma unroll
        for (int off = 1; off <= 32; off <<= 1)
            acc += __shfl_xor(acc, off, 64);
        if (l == 0)
            atomicAdd(out, acc + sPos);
    }
}

extern "C" void kernel_launch(void* const* d_in, const int* in_sizes, int n_in,
                              void* d_out, int out_size, void* d_ws, size_t ws_size,
                              hipStream_t stream)
{
    const float* user_emb = (const float*)d_in[0];
    const float* item_emb = (const float*)d_in[1];
    const float* w_user   = (const float*)d_in[2];
    const float* w_item   = (const float*)d_in[3];
    const float* bias     = (const float*)d_in[4];
    const float* h1       = (const float*)d_in[5];
    const float* h2       = (const float*)d_in[6];
    const int*   ufeat    = (const int*)d_in[7];
    const int*   ifeat    = (const int*)d_in[8];
    const int*   pu       = (const int*)d_in[9];
    const int*   pi       = (const int*)d_in[10];

    const int U  = in_sizes[7] / FD;
    const int V  = in_sizes[8] / FD;
    const int P  = in_sizes[9];

    float* ws = (float*)d_ws;
    size_t off = 0;
    unsigned short* p_bf = (unsigned short*)(ws + off); off += (size_t)U * DD / 2;
    unsigned short* q_bf = (unsigned short*)(ws + off); off += (size_t)V * DD / 2;
    float* su   = ws + off; off += (size_t)U;          off = (off + 63) & ~(size_t)63;
    float* sv   = ws + off; off += (size_t)V;          off = (off + 63) & ~(size_t)63;
    float* PA   = ws + off; off += (size_t)GA * DD * DD;
    float* PB   = ws + off; off += (size_t)GB * DD * DD;
    float* posPart = ws + off; off += (size_t)POSB;    off = (off + 63) & ~(size_t)63;

    float* out = (float*)d_out;

    int nent = U + V;
    int nwaves = (nent + 3) / 4;             // 4 entities per wave
    entity_kernel<<<(nwaves + 3) / 4, 256, 0, stream>>>(
        user_emb, item_emb, w_user, w_item, bias, h1,
        ufeat, ifeat, p_bf, su, q_bf, sv, U, V, out, out_size);

    mid_kernel<<<GAB + GBB + POSB, 256, 0, stream>>>(
        p_bf, U, PA, q_bf, V, PB, su, sv, h2, pu, pi, P, posPart);

    neg_reduce_kernel<<<NEGB, 256, 0, stream>>>(PA, PB, h2, posPart, out);
}

// Round 6
// 149.003 us; speedup vs baseline: 2.1498x; 1.0503x over previous
//
#include <hip/hip_runtime.h>

#define FD 20
#define DD 64

#define GA 64     // gram partials for A (users)  = GAB blocks * 4 waves
#define GB 128    // gram partials for B (items)  = GBB blocks * 4 waves
#define GAB 16    // gram blocks for A
#define GBB 32    // gram blocks for B
#define POSB 2048 // pos blocks in fused mid kernel
#define NEGB 64   // neg reduce blocks (one Gram row each)

typedef float float2v __attribute__((ext_vector_type(2)));
typedef float float4v __attribute__((ext_vector_type(4)));
typedef unsigned short ushort4v __attribute__((ext_vector_type(4)));
typedef unsigned short ushort8v __attribute__((ext_vector_type(8)));
typedef short short8v __attribute__((ext_vector_type(8)));

__device__ __forceinline__ unsigned short f2bf(float f) {
    unsigned u = __float_as_uint(f);
    unsigned r = u + 0x7fffu + ((u >> 16) & 1u);   // round-to-nearest-even
    return (unsigned short)(r >> 16);
}
__device__ __forceinline__ float bf2f(unsigned short h) {
    return __uint_as_float((unsigned)h << 16);
}

// ---------------------------------------------------------------------------
// Kernel 0: fp32 -> fp8 e4m3 (OCP) conversion of both embedding tables via
// HW v_cvt_pk_fp8_f32, plus zero-init of d_out. The fp32 source is read
// NON-TEMPORALLY (pure stream, zero reuse) so it doesn't evict the fp8
// tables being written -- those are the next kernel's gather working set
// (r5 lesson: fp8 tables L2-fit is worth ~44 us vs fp32 gathers).
// ---------------------------------------------------------------------------
__global__ __launch_bounds__(256) void conv_kernel(
    const float* __restrict__ ue, const float* __restrict__ ie,
    unsigned int* __restrict__ u8, unsigned int* __restrict__ i8,
    int n4, float* __restrict__ out, int out_size)
{
    int i = blockIdx.x * blockDim.x + threadIdx.x;
    if (i < out_size) out[i] = 0.0f;
    if (i >= 2 * n4) return;
    const float4v* src; unsigned int* dst; int k;
    if (i < n4) { src = (const float4v*)ue; dst = u8; k = i; }
    else        { src = (const float4v*)ie; dst = i8; k = i - n4; }
    float4v v = __builtin_nontemporal_load(&src[k]);
    unsigned int p = 0;
    p = __builtin_amdgcn_cvt_pk_fp8_f32(v.x, v.y, p, false);  // bytes 0,1
    p = __builtin_amdgcn_cvt_pk_fp8_f32(v.z, v.w, p, true);   // bytes 2,3
    dst[k] = p;
}

// ---------------------------------------------------------------------------
// Kernel 1 (r3-verified): 4 entities per wave, 16 lanes each. Lane (e,c)
// owns dims [4c,4c+4) of entity e across ALL 20 features:
//   - s/ss accumulation is lane-local (NO cross-lane reduction)
//   - packed v_cvt_pk_f32_fp8 decode (2 fp8 -> float2 per op)
//   - 20 independent 4B gathers in flight per lane
// ---------------------------------------------------------------------------
__global__ __launch_bounds__(256, 4) void entity_kernel(
    const unsigned char* __restrict__ user_f8,
    const unsigned char* __restrict__ item_f8,
    const float* __restrict__ w_user, const float* __restrict__ w_item,
    const float* __restrict__ bias, const float* __restrict__ h1,
    const int* __restrict__ ufeat, const int* __restrict__ ifeat,
    unsigned short* __restrict__ p_bf, float* __restrict__ su,
    unsigned short* __restrict__ q_bf, float* __restrict__ sv,
    int U, int V)
{
    int gwid = (int)((blockIdx.x * blockDim.x + threadIdx.x) >> 6);
    int lane = threadIdx.x & 63;
    int eg   = lane >> 4;            // entity slot within wave: 0..3
    int c    = lane & 15;            // dim chunk (4 dims)
    int ent  = gwid * 4 + eg;
    if (ent >= U + V) return;

    bool isU = ent < U;
    int  m   = isU ? ent : ent - U;
    const unsigned char* emb = isU ? user_f8 : item_f8;
    const float* wv   = isU ? w_user : w_item;
    const int*   fidx = (isU ? ufeat : ifeat) + (size_t)m * FD;
    float extra       = isU ? bias[0] : 0.0f;
    unsigned short* srow = (isU ? p_bf : q_bf) + (size_t)m * DD;
    float* sc         = (isU ? su : sv) + m;

    int idx[FD];
#pragma unroll
    for (int j = 0; j < FD; ++j) idx[j] = fidx[j];

    unsigned int hw[FD];
#pragma unroll
    for (int j = 0; j < FD; ++j)
        hw[j] = *((const unsigned int*)(emb + (size_t)idx[j] * DD) + c);

    float4v s4 = (float4v)0.0f, ss4 = (float4v)0.0f;
#pragma unroll
    for (int j = 0; j < FD; ++j) {
        float2v lo = __builtin_amdgcn_cvt_pk_f32_fp8(hw[j], false);
        float2v hi = __builtin_amdgcn_cvt_pk_f32_fp8(hw[j], true);
        float4v g;
        g.x = lo.x; g.y = lo.y; g.z = hi.x; g.w = hi.y;
        s4 += g; ss4 += g * g;
    }

    float part = wv[idx[c]];
    if (c < FD - 16) part += wv[idx[16 + c]];

    float4v h14 = *(const float4v*)(h1 + c * 4);
    float4v bi4 = 0.5f * (s4 * s4 - ss4);
    part += bi4.x*h14.x + bi4.y*h14.y + bi4.z*h14.z + bi4.w*h14.w;

#pragma unroll
    for (int off = 1; off <= 8; off <<= 1)
        part += __shfl_xor(part, off, 64);

    ushort4v o;
    o.x = f2bf(s4.x); o.y = f2bf(s4.y); o.z = f2bf(s4.z); o.w = f2bf(s4.w);
    *(ushort4v*)(srow + c * 4) = o;

    if (c == 0) *sc = part + extra;
}

// ---------------------------------------------------------------------------
// MFMA Gram partial, LDS-FREE (r2/r3-verified): one wave per 64-row tile
// stride; A-frag == B-frag; full 4x4 MFMA grid; full 64x64 partial store.
// C/D layout (m89-verified, r1-r3-passed): col = lane&15, row = (lane>>4)*4+reg.
// ---------------------------------------------------------------------------
__device__ __forceinline__ void gram_block_mfma(
    const unsigned short* __restrict__ M, int nrows, int gwid, int nw,
    float* __restrict__ Gpart)
{
    int lane = threadIdx.x & 63;
    int q = lane >> 4;
    int c = lane & 15;

    float4v acc[4][4];
#pragma unroll
    for (int ti = 0; ti < 4; ++ti)
#pragma unroll
        for (int tj = 0; tj < 4; ++tj)
            acc[ti][tj] = (float4v)0.0f;

    int ntiles = (nrows + 63) >> 6;
    for (int tt = gwid; tt < ntiles; tt += nw) {
        int row0 = tt << 6;
#pragma unroll
        for (int kb = 0; kb < 2; ++kb) {
            int r0 = row0 + kb * 32 + q * 8;
            const unsigned short* base = M + (size_t)r0 * DD + c;
            short8v f[4];
            if (row0 + 64 <= nrows) {
#pragma unroll
                for (int Db = 0; Db < 4; ++Db)
#pragma unroll
                    for (int j = 0; j < 8; ++j)
                        f[Db][j] = (short)base[(size_t)j * DD + Db * 16];
            } else {
#pragma unroll
                for (int Db = 0; Db < 4; ++Db)
#pragma unroll
                    for (int j = 0; j < 8; ++j)
                        f[Db][j] = (r0 + j < nrows)
                                 ? (short)base[(size_t)j * DD + Db * 16]
                                 : (short)0;
            }
#pragma unroll
            for (int ti = 0; ti < 4; ++ti)
#pragma unroll
                for (int tj = 0; tj < 4; ++tj)
                    acc[ti][tj] = __builtin_amdgcn_mfma_f32_16x16x32_bf16(
                        f[ti], f[tj], acc[ti][tj], 0, 0, 0);
        }
    }

    float* out = Gpart + (size_t)gwid * (DD * DD);
#pragma unroll
    for (int ti = 0; ti < 4; ++ti)
#pragma unroll
        for (int tj = 0; tj < 4; ++tj)
#pragma unroll
            for (int rg = 0; rg < 4; ++rg)
                out[(ti * 16 + q * 4 + rg) * DD + tj * 16 + c] = acc[ti][tj][rg];
}

// ---------------------------------------------------------------------------
// Kernel 2 (fused, identical to r3): gram blocks + pos blocks.
// ---------------------------------------------------------------------------
__global__ __launch_bounds__(256) void mid_kernel(
    const unsigned short* __restrict__ p_bf, int U, float* __restrict__ PA,
    const unsigned short* __restrict__ q_bf, int V, float* __restrict__ PB,
    const float* __restrict__ su, const float* __restrict__ sv,
    const float* __restrict__ h2,
    const int* __restrict__ pu, const int* __restrict__ pi,
    int P, float* __restrict__ posPart)
{
    __shared__ float red[4];
    int w = threadIdx.x >> 6;

    if (blockIdx.x < GAB) {
        gram_block_mfma(p_bf, U, blockIdx.x * 4 + w, GA, PA);
        return;
    }
    if (blockIdx.x < GAB + GBB) {
        gram_block_mfma(q_bf, V, (blockIdx.x - GAB) * 4 + w, GB, PB);
        return;
    }

    // ---- positive-pair part ----
    int lane = threadIdx.x & 63;
    int sl   = lane & 15;
    int sub  = lane >> 4;
    int pb   = blockIdx.x - (GAB + GBB);
    int wId  = pb * 4 + w;
    const int NW = POSB * 4;                 // 8192 waves

    float4v h2v = *(const float4v*)(h2 + sl * 4);

    int pid0 = wId * 4 + sub;                // [0, 32768)
    int pid1 = pid0 + NW * 4;                // [32768, 65536)
    bool ok0 = pid0 < P, ok1 = pid1 < P;

    int u0 = 0, v0 = 0, u1 = 0, v1 = 0;
    if (ok0) { u0 = pu[pid0]; v0 = pi[pid0]; }
    if (ok1) { u1 = pu[pid1]; v1 = pi[pid1]; }

    ushort4v ph0 = (ushort4v)0, qh0 = (ushort4v)0;
    ushort4v ph1 = (ushort4v)0, qh1 = (ushort4v)0;
    if (ok0) {
        ph0 = *(const ushort4v*)(p_bf + (size_t)u0 * DD + sl * 4);
        qh0 = *(const ushort4v*)(q_bf + (size_t)v0 * DD + sl * 4);
    }
    if (ok1) {
        ph1 = *(const ushort4v*)(p_bf + (size_t)u1 * DD + sl * 4);
        qh1 = *(const ushort4v*)(q_bf + (size_t)v1 * DD + sl * 4);
    }

    float d0 = bf2f(ph0.x)*bf2f(qh0.x)*h2v.x + bf2f(ph0.y)*bf2f(qh0.y)*h2v.y
             + bf2f(ph0.z)*bf2f(qh0.z)*h2v.z + bf2f(ph0.w)*bf2f(qh0.w)*h2v.w;
    float d1 = bf2f(ph1.x)*bf2f(qh1.x)*h2v.x + bf2f(ph1.y)*bf2f(qh1.y)*h2v.y
             + bf2f(ph1.z)*bf2f(qh1.z)*h2v.z + bf2f(ph1.w)*bf2f(qh1.w)*h2v.w;
#pragma unroll
    for (int off = 1; off < 16; off <<= 1) {
        d0 += __shfl_xor(d0, off, 64);
        d1 += __shfl_xor(d1, off, 64);
    }

    float acc = 0.0f;
    if (sl == 0) {
        if (ok0) { float y = d0 + su[u0] + sv[v0]; acc += 0.5f * y * y - 2.0f * y; }
        if (ok1) { float y = d1 + su[u1] + sv[v1]; acc += 0.5f * y * y - 2.0f * y; }
    }
    acc += __shfl_xor(acc, 16, 64);
    acc += __shfl_xor(acc, 32, 64);
    if (lane == 0) red[w] = acc;
    __syncthreads();
    if (threadIdx.x == 0)
        posPart[pb] = red[0] + red[1] + red[2] + red[3];
}

// ---------------------------------------------------------------------------
// Kernel 3 (identical to r3): reduce gram partials + pos partials.
// ---------------------------------------------------------------------------
__global__ __launch_bounds__(256) void neg_reduce_kernel(
    const float* __restrict__ PA, const float* __restrict__ PB,
    const float* __restrict__ h2, const float* __restrict__ posPart,
    float* __restrict__ out)
{
    __shared__ float sA[4][64], sB[4][64];
    __shared__ float sPos;
    int t  = threadIdx.x;
    int l  = t & 63;
    int ch = t >> 6;                       // k-chunk 0..3
    int e  = blockIdx.x * 64 + l;          // Gram entry, i=blockIdx.x, j=l

    float a = 0.0f, b = 0.0f;
#pragma unroll
    for (int k = 0; k < GA / 4; ++k)       // 16 coalesced loads
        a += PA[(size_t)(ch * (GA / 4) + k) * (DD * DD) + e];
#pragma unroll
    for (int k = 0; k < GB / 4; ++k)       // 32 coalesced loads
        b += PB[(size_t)(ch * (GB / 4) + k) * (DD * DD) + e];
    sA[ch][l] = a;
    sB[ch][l] = b;

    if (ch == 1) {                         // wave 1: fold 32 pos partials
        float p = (l < POSB / NEGB) ? posPart[blockIdx.x * (POSB / NEGB) + l] : 0.0f;
#pragma unroll
        for (int off = 1; off <= 32; off <<= 1)
            p += __shfl_xor(p, off, 64);
        if (l == 0) sPos = p;
    }
    __syncthreads();

    if (ch == 0) {
        float fa = sA[0][l] + sA[1][l] + sA[2][l] + sA[3][l];
        float fb = sB[0][l] + sB[1][l] + sB[2][l] + sB[3][l];
        float acc = 0.5f * h2[blockIdx.x] * h2[l] * fa * fb;
#pragma unroll
        for (int off = 1; off <= 32; off <<= 1)
            acc += __shfl_xor(acc, off, 64);
        if (l == 0)
            atomicAdd(out, acc + sPos);
    }
}

extern "C" void kernel_launch(void* const* d_in, const int* in_sizes, int n_in,
                              void* d_out, int out_size, void* d_ws, size_t ws_size,
                              hipStream_t stream)
{
    const float* user_emb = (const float*)d_in[0];
    const float* item_emb = (const float*)d_in[1];
    const float* w_user   = (const float*)d_in[2];
    const float* w_item   = (const float*)d_in[3];
    const float* bias     = (const float*)d_in[4];
    const float* h1       = (const float*)d_in[5];
    const float* h2       = (const float*)d_in[6];
    const int*   ufeat    = (const int*)d_in[7];
    const int*   ifeat    = (const int*)d_in[8];
    const int*   pu       = (const int*)d_in[9];
    const int*   pi       = (const int*)d_in[10];

    const int NF = in_sizes[0] / DD;
    const int U  = in_sizes[7] / FD;
    const int V  = in_sizes[8] / FD;
    const int P  = in_sizes[9];

    float* ws = (float*)d_ws;
    size_t off = 0;
    unsigned short* p_bf = (unsigned short*)(ws + off); off += (size_t)U * DD / 2;
    unsigned short* q_bf = (unsigned short*)(ws + off); off += (size_t)V * DD / 2;
    float* su   = ws + off; off += (size_t)U;          off = (off + 63) & ~(size_t)63;
    float* sv   = ws + off; off += (size_t)V;          off = (off + 63) & ~(size_t)63;
    float* PA   = ws + off; off += (size_t)GA * DD * DD;
    float* PB   = ws + off; off += (size_t)GB * DD * DD;
    float* posPart = ws + off; off += (size_t)POSB;    off = (off + 63) & ~(size_t)63;
    unsigned char* uf8 = (unsigned char*)(ws + off);   off += (size_t)NF * DD / 4;
    unsigned char* if8 = (unsigned char*)(ws + off);   off += (size_t)NF * DD / 4;

    float* out = (float*)d_out;

    int n4 = NF * DD / 4;
    conv_kernel<<<(2 * n4 + 255) / 256, 256, 0, stream>>>(
        user_emb, item_emb, (unsigned int*)uf8, (unsigned int*)if8,
        n4, out, out_size);

    int nent = U + V;
    int nwaves = (nent + 3) / 4;             // 4 entities per wave
    entity_kernel<<<(nwaves + 3) / 4, 256, 0, stream>>>(
        uf8, if8, w_user, w_item, bias, h1,
        ufeat, ifeat, p_bf, su, q_bf, sv, U, V);

    mid_kernel<<<GAB + GBB + POSB, 256, 0, stream>>>(
        p_bf, U, PA, q_bf, V, PB, su, sv, h2, pu, pi, P, posPart);

    neg_reduce_kernel<<<NEGB, 256, 0, stream>>>(PA, PB, h2, posPart, out);
}

// Round 7
// 144.588 us; speedup vs baseline: 2.2155x; 1.0305x over previous
//
#include <hip/hip_runtime.h>

#define FD 20
#define DD 64

#define GA 64     // gram partials for A (users)  = GAB blocks * 4 waves
#define GB 128    // gram partials for B (items)  = GBB blocks * 4 waves
#define GAB 16    // gram blocks for A
#define GBB 32    // gram blocks for B
#define POSB 2048 // pos blocks in fused mid kernel
#define NEGB 64   // neg reduce blocks (one Gram row each)

typedef float float2v __attribute__((ext_vector_type(2)));
typedef float float4v __attribute__((ext_vector_type(4)));
typedef unsigned short ushort4v __attribute__((ext_vector_type(4)));
typedef unsigned short ushort8v __attribute__((ext_vector_type(8)));
typedef short short8v __attribute__((ext_vector_type(8)));

__device__ __forceinline__ unsigned short f2bf(float f) {
    unsigned u = __float_as_uint(f);
    unsigned r = u + 0x7fffu + ((u >> 16) & 1u);   // round-to-nearest-even
    return (unsigned short)(r >> 16);
}
__device__ __forceinline__ float bf2f(unsigned short h) {
    return __uint_as_float((unsigned)h << 16);
}

// ---------------------------------------------------------------------------
// Kernel 0: fp32 -> fp8 e4m3 (OCP) conversion of both embedding tables via
// HW v_cvt_pk_fp8_f32, plus zero-init of d_out.
// NOTE (r5/r6 lessons): this pass is load-bearing cache compaction -- fp8
// tables (12.8 MB) L2-fit where fp32 gathers miss (r5: +44 us). Plain
// cached loads; nontemporal was tried (r6) and was neutral-to-harmful.
// ---------------------------------------------------------------------------
__global__ __launch_bounds__(256) void conv_kernel(
    const float* __restrict__ ue, const float* __restrict__ ie,
    unsigned int* __restrict__ u8, unsigned int* __restrict__ i8,
    int n4, float* __restrict__ out, int out_size)
{
    int i = blockIdx.x * blockDim.x + threadIdx.x;
    if (i < out_size) out[i] = 0.0f;
    if (i >= 2 * n4) return;
    const float4v* src; unsigned int* dst; int k;
    if (i < n4) { src = (const float4v*)ue; dst = u8; k = i; }
    else        { src = (const float4v*)ie; dst = i8; k = i - n4; }
    float4v v = src[k];
    unsigned int p = 0;
    p = __builtin_amdgcn_cvt_pk_fp8_f32(v.x, v.y, p, false);  // bytes 0,1
    p = __builtin_amdgcn_cvt_pk_fp8_f32(v.z, v.w, p, true);   // bytes 2,3
    dst[k] = p;
}

// ---------------------------------------------------------------------------
// Kernel 1 (r3-verified): 4 entities per wave, 16 lanes each. Lane (e,c)
// owns dims [4c,4c+4) of entity e across ALL 20 features:
//   - s/ss accumulation is lane-local (NO cross-lane reduction)
//   - packed v_cvt_pk_f32_fp8 decode (2 fp8 -> float2 per op)
//   - 20 independent 4B gathers in flight per lane
// ---------------------------------------------------------------------------
__global__ __launch_bounds__(256, 4) void entity_kernel(
    const unsigned char* __restrict__ user_f8,
    const unsigned char* __restrict__ item_f8,
    const float* __restrict__ w_user, const float* __restrict__ w_item,
    const float* __restrict__ bias, const float* __restrict__ h1,
    const int* __restrict__ ufeat, const int* __restrict__ ifeat,
    unsigned short* __restrict__ p_bf, float* __restrict__ su,
    unsigned short* __restrict__ q_bf, float* __restrict__ sv,
    int U, int V)
{
    int gwid = (int)((blockIdx.x * blockDim.x + threadIdx.x) >> 6);
    int lane = threadIdx.x & 63;
    int eg   = lane >> 4;            // entity slot within wave: 0..3
    int c    = lane & 15;            // dim chunk (4 dims)
    int ent  = gwid * 4 + eg;
    if (ent >= U + V) return;

    bool isU = ent < U;
    int  m   = isU ? ent : ent - U;
    const unsigned char* emb = isU ? user_f8 : item_f8;
    const float* wv   = isU ? w_user : w_item;
    const int*   fidx = (isU ? ufeat : ifeat) + (size_t)m * FD;
    float extra       = isU ? bias[0] : 0.0f;
    unsigned short* srow = (isU ? p_bf : q_bf) + (size_t)m * DD;
    float* sc         = (isU ? su : sv) + m;

    int idx[FD];
#pragma unroll
    for (int j = 0; j < FD; ++j) idx[j] = fidx[j];

    unsigned int hw[FD];
#pragma unroll
    for (int j = 0; j < FD; ++j)
        hw[j] = *((const unsigned int*)(emb + (size_t)idx[j] * DD) + c);

    float4v s4 = (float4v)0.0f, ss4 = (float4v)0.0f;
#pragma unroll
    for (int j = 0; j < FD; ++j) {
        float2v lo = __builtin_amdgcn_cvt_pk_f32_fp8(hw[j], false);
        float2v hi = __builtin_amdgcn_cvt_pk_f32_fp8(hw[j], true);
        float4v g;
        g.x = lo.x; g.y = lo.y; g.z = hi.x; g.w = hi.y;
        s4 += g; ss4 += g * g;
    }

    float part = wv[idx[c]];
    if (c < FD - 16) part += wv[idx[16 + c]];

    float4v h14 = *(const float4v*)(h1 + c * 4);
    float4v bi4 = 0.5f * (s4 * s4 - ss4);
    part += bi4.x*h14.x + bi4.y*h14.y + bi4.z*h14.z + bi4.w*h14.w;

#pragma unroll
    for (int off = 1; off <= 8; off <<= 1)
        part += __shfl_xor(part, off, 64);

    ushort4v o;
    o.x = f2bf(s4.x); o.y = f2bf(s4.y); o.z = f2bf(s4.z); o.w = f2bf(s4.w);
    *(ushort4v*)(srow + c * 4) = o;

    if (c == 0) *sc = part + extra;
}

// ---------------------------------------------------------------------------
// MFMA Gram partial, LDS-FREE (r2/r3-verified): one wave per 64-row tile
// stride; A-frag == B-frag; full 4x4 MFMA grid; full 64x64 partial store.
// C/D layout (m89-verified, r1-r3-passed): col = lane&15, row = (lane>>4)*4+reg.
// ---------------------------------------------------------------------------
__device__ __forceinline__ void gram_block_mfma(
    const unsigned short* __restrict__ M, int nrows, int gwid, int nw,
    float* __restrict__ Gpart)
{
    int lane = threadIdx.x & 63;
    int q = lane >> 4;
    int c = lane & 15;

    float4v acc[4][4];
#pragma unroll
    for (int ti = 0; ti < 4; ++ti)
#pragma unroll
        for (int tj = 0; tj < 4; ++tj)
            acc[ti][tj] = (float4v)0.0f;

    int ntiles = (nrows + 63) >> 6;
    for (int tt = gwid; tt < ntiles; tt += nw) {
        int row0 = tt << 6;
#pragma unroll
        for (int kb = 0; kb < 2; ++kb) {
            int r0 = row0 + kb * 32 + q * 8;
            const unsigned short* base = M + (size_t)r0 * DD + c;
            short8v f[4];
            if (row0 + 64 <= nrows) {
#pragma unroll
                for (int Db = 0; Db < 4; ++Db)
#pragma unroll
                    for (int j = 0; j < 8; ++j)
                        f[Db][j] = (short)base[(size_t)j * DD + Db * 16];
            } else {
#pragma unroll
                for (int Db = 0; Db < 4; ++Db)
#pragma unroll
                    for (int j = 0; j < 8; ++j)
                        f[Db][j] = (r0 + j < nrows)
                                 ? (short)base[(size_t)j * DD + Db * 16]
                                 : (short)0;
            }
#pragma unroll
            for (int ti = 0; ti < 4; ++ti)
#pragma unroll
                for (int tj = 0; tj < 4; ++tj)
                    acc[ti][tj] = __builtin_amdgcn_mfma_f32_16x16x32_bf16(
                        f[ti], f[tj], acc[ti][tj], 0, 0, 0);
        }
    }

    float* out = Gpart + (size_t)gwid * (DD * DD);
#pragma unroll
    for (int ti = 0; ti < 4; ++ti)
#pragma unroll
        for (int tj = 0; tj < 4; ++tj)
#pragma unroll
            for (int rg = 0; rg < 4; ++rg)
                out[(ti * 16 + q * 4 + rg) * DD + tj * 16 + c] = acc[ti][tj][rg];
}

// ---------------------------------------------------------------------------
// Kernel 2 (fused, identical to r3): gram blocks + pos blocks.
// ---------------------------------------------------------------------------
__global__ __launch_bounds__(256) void mid_kernel(
    const unsigned short* __restrict__ p_bf, int U, float* __restrict__ PA,
    const unsigned short* __restrict__ q_bf, int V, float* __restrict__ PB,
    const float* __restrict__ su, const float* __restrict__ sv,
    const float* __restrict__ h2,
    const int* __restrict__ pu, const int* __restrict__ pi,
    int P, float* __restrict__ posPart)
{
    __shared__ float red[4];
    int w = threadIdx.x >> 6;

    if (blockIdx.x < GAB) {
        gram_block_mfma(p_bf, U, blockIdx.x * 4 + w, GA, PA);
        return;
    }
    if (blockIdx.x < GAB + GBB) {
        gram_block_mfma(q_bf, V, (blockIdx.x - GAB) * 4 + w, GB, PB);
        return;
    }

    // ---- positive-pair part ----
    int lane = threadIdx.x & 63;
    int sl   = lane & 15;
    int sub  = lane >> 4;
    int pb   = blockIdx.x - (GAB + GBB);
    int wId  = pb * 4 + w;
    const int NW = POSB * 4;                 // 8192 waves

    float4v h2v = *(const float4v*)(h2 + sl * 4);

    int pid0 = wId * 4 + sub;                // [0, 32768)
    int pid1 = pid0 + NW * 4;                // [32768, 65536)
    bool ok0 = pid0 < P, ok1 = pid1 < P;

    int u0 = 0, v0 = 0, u1 = 0, v1 = 0;
    if (ok0) { u0 = pu[pid0]; v0 = pi[pid0]; }
    if (ok1) { u1 = pu[pid1]; v1 = pi[pid1]; }

    ushort4v ph0 = (ushort4v)0, qh0 = (ushort4v)0;
    ushort4v ph1 = (ushort4v)0, qh1 = (ushort4v)0;
    if (ok0) {
        ph0 = *(const ushort4v*)(p_bf + (size_t)u0 * DD + sl * 4);
        qh0 = *(const ushort4v*)(q_bf + (size_t)v0 * DD + sl * 4);
    }
    if (ok1) {
        ph1 = *(const ushort4v*)(p_bf + (size_t)u1 * DD + sl * 4);
        qh1 = *(const ushort4v*)(q_bf + (size_t)v1 * DD + sl * 4);
    }

    float d0 = bf2f(ph0.x)*bf2f(qh0.x)*h2v.x + bf2f(ph0.y)*bf2f(qh0.y)*h2v.y
             + bf2f(ph0.z)*bf2f(qh0.z)*h2v.z + bf2f(ph0.w)*bf2f(qh0.w)*h2v.w;
    float d1 = bf2f(ph1.x)*bf2f(qh1.x)*h2v.x + bf2f(ph1.y)*bf2f(qh1.y)*h2v.y
             + bf2f(ph1.z)*bf2f(qh1.z)*h2v.z + bf2f(ph1.w)*bf2f(qh1.w)*h2v.w;
#pragma unroll
    for (int off = 1; off < 16; off <<= 1) {
        d0 += __shfl_xor(d0, off, 64);
        d1 += __shfl_xor(d1, off, 64);
    }

    float acc = 0.0f;
    if (sl == 0) {
        if (ok0) { float y = d0 + su[u0] + sv[v0]; acc += 0.5f * y * y - 2.0f * y; }
        if (ok1) { float y = d1 + su[u1] + sv[v1]; acc += 0.5f * y * y - 2.0f * y; }
    }
    acc += __shfl_xor(acc, 16, 64);
    acc += __shfl_xor(acc, 32, 64);
    if (lane == 0) red[w] = acc;
    __syncthreads();
    if (threadIdx.x == 0)
        posPart[pb] = red[0] + red[1] + red[2] + red[3];
}

// ---------------------------------------------------------------------------
// Kernel 3 (identical to r3): reduce gram partials + pos partials.
// ---------------------------------------------------------------------------
__global__ __launch_bounds__(256) void neg_reduce_kernel(
    const float* __restrict__ PA, const float* __restrict__ PB,
    const float* __restrict__ h2, const float* __restrict__ posPart,
    float* __restrict__ out)
{
    __shared__ float sA[4][64], sB[4][64];
    __shared__ float sPos;
    int t  = threadIdx.x;
    int l  = t & 63;
    int ch = t >> 6;                       // k-chunk 0..3
    int e  = blockIdx.x * 64 + l;          // Gram entry, i=blockIdx.x, j=l

    float a = 0.0f, b = 0.0f;
#pragma unroll
    for (int k = 0; k < GA / 4; ++k)       // 16 coalesced loads
        a += PA[(size_t)(ch * (GA / 4) + k) * (DD * DD) + e];
#pragma unroll
    for (int k = 0; k < GB / 4; ++k)       // 32 coalesced loads
        b += PB[(size_t)(ch * (GB / 4) + k) * (DD * DD) + e];
    sA[ch][l] = a;
    sB[ch][l] = b;

    if (ch == 1) {                         // wave 1: fold 32 pos partials
        float p = (l < POSB / NEGB) ? posPart[blockIdx.x * (POSB / NEGB) + l] : 0.0f;
#pragma unroll
        for (int off = 1; off <= 32; off <<= 1)
            p += __shfl_xor(p, off, 64);
        if (l == 0) sPos = p;
    }
    __syncthreads();

    if (ch == 0) {
        float fa = sA[0][l] + sA[1][l] + sA[2][l] + sA[3][l];
        float fb = sB[0][l] + sB[1][l] + sB[2][l] + sB[3][l];
        float acc = 0.5f * h2[blockIdx.x] * h2[l] * fa * fb;
#pragma unroll
        for (int off = 1; off <= 32; off <<= 1)
            acc += __shfl_xor(acc, off, 64);
        if (l == 0)
            atomicAdd(out, acc + sPos);
    }
}

extern "C" void kernel_launch(void* const* d_in, const int* in_sizes, int n_in,
                              void* d_out, int out_size, void* d_ws, size_t ws_size,
                              hipStream_t stream)
{
    const float* user_emb = (const float*)d_in[0];
    const float* item_emb = (const float*)d_in[1];
    const float* w_user   = (const float*)d_in[2];
    const float* w_item   = (const float*)d_in[3];
    const float* bias     = (const float*)d_in[4];
    const float* h1       = (const float*)d_in[5];
    const float* h2       = (const float*)d_in[6];
    const int*   ufeat    = (const int*)d_in[7];
    const int*   ifeat    = (const int*)d_in[8];
    const int*   pu       = (const int*)d_in[9];
    const int*   pi       = (const int*)d_in[10];

    const int NF = in_sizes[0] / DD;
    const int U  = in_sizes[7] / FD;
    const int V  = in_sizes[8] / FD;
    const int P  = in_sizes[9];

    float* ws = (float*)d_ws;
    size_t off = 0;
    unsigned short* p_bf = (unsigned short*)(ws + off); off += (size_t)U * DD / 2;
    unsigned short* q_bf = (unsigned short*)(ws + off); off += (size_t)V * DD / 2;
    float* su   = ws + off; off += (size_t)U;          off = (off + 63) & ~(size_t)63;
    float* sv   = ws + off; off += (size_t)V;          off = (off + 63) & ~(size_t)63;
    float* PA   = ws + off; off += (size_t)GA * DD * DD;
    float* PB   = ws + off; off += (size_t)GB * DD * DD;
    float* posPart = ws + off; off += (size_t)POSB;    off = (off + 63) & ~(size_t)63;
    unsigned char* uf8 = (unsigned char*)(ws + off);   off += (size_t)NF * DD / 4;
    unsigned char* if8 = (unsigned char*)(ws + off);   off += (size_t)NF * DD / 4;

    float* out = (float*)d_out;

    int n4 = NF * DD / 4;
    conv_kernel<<<(2 * n4 + 255) / 256, 256, 0, stream>>>(
        user_emb, item_emb, (unsigned int*)uf8, (unsigned int*)if8,
        n4, out, out_size);

    int nent = U + V;
    int nwaves = (nent + 3) / 4;             // 4 entities per wave
    entity_kernel<<<(nwaves + 3) / 4, 256, 0, stream>>>(
        uf8, if8, w_user, w_item, bias, h1,
        ufeat, ifeat, p_bf, su, q_bf, sv, U, V);

    mid_kernel<<<GAB + GBB + POSB, 256, 0, stream>>>(
        p_bf, U, PA, q_bf, V, PB, su, sv, h2, pu, pi, P, posPart);

    neg_reduce_kernel<<<NEGB, 256, 0, stream>>>(PA, PB, h2, posPart, out);
}